// Round 9
// baseline (58.528 us; speedup 1.0000x reference)
//
#include <hip/hip_runtime.h>
#include <hip/hip_bf16.h>

// Problem: B=8192, DIM_IN=2048, DIM_OUT=512
//   hazards = relu(x @ W_h^T + b_h)            [8192,512]
//   out     = cumsum(hazards, axis=1) + (x @ W_base^T + b_base)
//
// Round 9: B via global_load_lds DMA (no VGPR staging, no compiler sinking,
// full 64KB/phase in flight), double-buffered LDS; vmcnt(0) AFTER compute +
// no-drain barrier per phase (m97 structure). A reg-staged (2 f32/thread),
// dbuf. Fused scan epilogue unchanged.

typedef __attribute__((ext_vector_type(8))) short  short8;
typedef __attribute__((ext_vector_type(4))) float  float4v;
typedef __attribute__((ext_vector_type(4))) float  f32x4;
typedef __attribute__((ext_vector_type(2))) float  float2v;

#define DIN  2048
#define DOUT 512
#define NROW 8192
#define BM   32
#define NPH  (DIN / 64)   // 32 K-phases of 64

static __device__ __forceinline__ unsigned short f2bf(float f) {
  union { float f; unsigned int u; } v; v.f = f;
  unsigned int u = v.u;
  unsigned int r = (u + 0x7FFFu + ((u >> 16) & 1u)) >> 16;   // RNE
  return (unsigned short)r;
}

// async 16B/lane global->LDS DMA: lds dest = uniform base + lane*16
static __device__ __forceinline__ void dma16(const unsigned short* g,
                                             unsigned short* l) {
  __builtin_amdgcn_global_load_lds(
      (const __attribute__((address_space(1))) unsigned int*)g,
      (__attribute__((address_space(3))) unsigned int*)l, 16, 0, 0);
}

static __device__ __forceinline__ void barrier_nd() {
  asm volatile("s_waitcnt lgkmcnt(0)" ::: "memory");
  __builtin_amdgcn_s_barrier();
}

// ---- k_pack: W[512][2048] f32 -> fragment-packed bf16 ---------------------
// fragment (nt, ktp): nt = n>>4 (32), ktp = k>>5 (64).
// lane slot: n = nt*16 + (lane&15), k = ktp*32 + (lane>>4)*8 (+e)
// storage: Wp[ ((nt*64 + ktp)*64 + lane)*8 + e ] -> each frag = 1KB contig.
__global__ __launch_bounds__(256) void k_pack(const float* __restrict__ W,
                                              unsigned short* __restrict__ Wp) {
  int t    = blockIdx.x * 256 + threadIdx.x;   // 0..131071
  int lane = t & 63;
  int frag = t >> 6;
  int nt   = frag >> 6, ktp = frag & 63;
  int n = nt * 16 + (lane & 15);
  int k = ktp * 32 + (lane >> 4) * 8;
  const float* src = W + (size_t)n * DIN + k;
  float4v a = *(const float4v*)src;
  float4v b = *(const float4v*)(src + 4);
  unsigned short o[8] = { f2bf(a.x), f2bf(a.y), f2bf(a.z), f2bf(a.w),
                          f2bf(b.x), f2bf(b.y), f2bf(b.z), f2bf(b.w) };
  *(short8*)(Wp + (size_t)t * 8) = *(const short8*)o;
}

// ---- k_main: fused GEMM + bias + relu + row-scan + base -------------------
// grid 256 (BM=32 rows), 1024 threads = 16 waves; wave w owns cols 32w..32w+31
// (ni 0..1). acc[mi][ni]: out rows mi*16+(lane&15), cols ni*16+(lane>>4)*4+r.
__global__ __launch_bounds__(1024) void k_main(
    const float* __restrict__ x, const unsigned short* __restrict__ Wp,
    const float* __restrict__ b_h, const float* __restrict__ w_base,
    const float* __restrict__ b_base, float* __restrict__ out) {
  __shared__ unsigned short Bb[2][32 * 1024];  // 2 x 64 KB (64 frags x 1KB)
  __shared__ unsigned short Aa[2][BM * 64];    // 2 x 4 KB, XOR-swizzled
  __shared__ float WbL[DIN];                   // 8 KB base weights
  __shared__ float stripT[BM][16];
  __shared__ float baseL[BM];

  const int tid  = threadIdx.x;
  const int lane = tid & 63;
  const int w    = tid >> 6;       // wave 0..15
  const int q    = lane >> 4;      // 0..3
  const int lm   = lane & 15;
  const int m0   = blockIdx.x * BM;

  // A staging: row sr = tid>>5 (0..31), 2 k-cols at c2 = (tid&31)*2
  const int sr  = tid >> 5;
  const int c2  = (tid & 31) * 2;
  const int sgA = c2 >> 3;                       // granule 0..7
  const int aOff = sr * 64 + ((sgA ^ (sr & 7)) << 3) + (c2 & 7);  // ushort idx

  ((float2v*)WbL)[tid] = ((const float2v*)w_base)[tid];  // 8 KB fill

  f32x4 acc[2][2];
  const f32x4 z4 = {0.f, 0.f, 0.f, 0.f};
#pragma unroll
  for (int mi = 0; mi < 2; ++mi)
#pragma unroll
    for (int ni = 0; ni < 2; ++ni) acc[mi][ni] = z4;

  float2v aNext;
  float   basePart = 0.f;

  auto dmaB = [&](int p, int buf) {   // 4 frags per wave: f = 4w..4w+3
#pragma unroll
    for (int j = 0; j < 4; ++j) {
      const int f = w * 4 + j;
      const int fg = (f >> 1) * 64 + p * 2 + (f & 1);   // global frag index
      dma16(Wp + (size_t)fg * 512 + lane * 8, &Bb[buf][f * 512]);
    }
  };
  auto loadA = [&](int p) {
    aNext = *(const float2v*)(x + (size_t)(m0 + sr) * DIN + p * 64 + c2);
  };
  auto stageA = [&](int p, unsigned short* Ad) {
    unsigned int pk = ((unsigned int)f2bf(aNext.x)) |
                      (((unsigned int)f2bf(aNext.y)) << 16);
    *(unsigned int*)&Ad[aOff] = pk;
    float2v wb = *(const float2v*)&WbL[p * 64 + c2];
    basePart += aNext.x * wb.x + aNext.y * wb.y;
  };
  auto compute = [&](const unsigned short* Bc, const unsigned short* Ac) {
    short8 bfr[2][2], xf[2][2];
#pragma unroll
    for (int h = 0; h < 2; ++h)
#pragma unroll
      for (int mi = 0; mi < 2; ++mi) {
        int r = mi * 16 + lm;
        int g = q + 4 * h;
        xf[h][mi] = *(const short8*)&Ac[r * 64 + ((g ^ (r & 7)) << 3)];
      }
#pragma unroll
    for (int ni = 0; ni < 2; ++ni)
#pragma unroll
      for (int h = 0; h < 2; ++h) {
        int f = 4 * w + 2 * ni + h;
        bfr[ni][h] = *(const short8*)&Bb[0][0];  // placeholder, replaced below
        bfr[ni][h] = *(const short8*)&Bc[f * 512 + lane * 8];
      }
#pragma unroll
    for (int h = 0; h < 2; ++h)
#pragma unroll
      for (int mi = 0; mi < 2; ++mi)
#pragma unroll
        for (int ni = 0; ni < 2; ++ni)
          acc[mi][ni] = __builtin_amdgcn_mfma_f32_16x16x32_bf16(
              bfr[ni][h], xf[h][mi], acc[mi][ni], 0, 0, 0);
  };

  // prologue: DMA B(0), load A(0); WbL barrier; stage A(0); full barrier
  dmaB(0, 0);
  loadA(0);
  barrier_nd();                    // WbL visible
  stageA(0, Aa[0]);
  asm volatile("s_waitcnt vmcnt(0)" ::: "memory");
  barrier_nd();                    // B(0) landed + A(0) visible

  for (int p = 0; p < NPH; ++p) {
    const int cur = p & 1, nxt = cur ^ 1;
    if (p + 1 < NPH) {
      dmaB(p + 1, nxt);            // async, stays in flight through compute
      loadA(p + 1);
    }
    compute(Bb[cur], Aa[cur]);
    if (p + 1 < NPH) stageA(p + 1, Aa[nxt]);
    asm volatile("s_waitcnt vmcnt(0)" ::: "memory");  // DMA done (hidden)
    barrier_nd();
  }

  // ---- base GEMV reduce: 32 consecutive threads share row sr ----
  {
    float s = basePart;
    s += __shfl_xor(s, 1);  s += __shfl_xor(s, 2);
    s += __shfl_xor(s, 4);  s += __shfl_xor(s, 8);
    s += __shfl_xor(s, 16);
    if ((tid & 31) == 0) baseL[sr] = s + b_base[0];
  }

  // ---- epilogue: bias + relu + scan over this wave's 32-col strip ----
  float runp[2][2][4];
  float Eq[2][2];
  float niPre[2][2];
  float Tst[2];
#pragma unroll
  for (int mi = 0; mi < 2; ++mi) {
    float run = 0.f;
#pragma unroll
    for (int ni = 0; ni < 2; ++ni) {
      float4v b4 = *(const float4v*)(b_h + w * 32 + ni * 16 + q * 4);
      f32x4 v = acc[mi][ni];
      float h0 = fmaxf(v.x + b4.x, 0.f);
      float h1 = fmaxf(v.y + b4.y, 0.f);
      float h2 = fmaxf(v.z + b4.z, 0.f);
      float h3 = fmaxf(v.w + b4.w, 0.f);
      runp[mi][ni][0] = h0;
      runp[mi][ni][1] = h0 + h1;
      runp[mi][ni][2] = h0 + h1 + h2;
      runp[mi][ni][3] = h0 + h1 + h2 + h3;
      float S = runp[mi][ni][3];
      float u1 = __shfl_up(S, 16);
      float u2 = __shfl_up(S, 32);
      float u3 = __shfl_up(S, 48);
      Eq[mi][ni] = (q >= 1 ? u1 : 0.f) + (q >= 2 ? u2 : 0.f) + (q >= 3 ? u3 : 0.f);
      float G = S + __shfl_xor(S, 16);
      G += __shfl_xor(G, 32);
      niPre[mi][ni] = run;
      run += G;
    }
    Tst[mi] = run;
  }
  if (q == 0) {
#pragma unroll
    for (int mi = 0; mi < 2; ++mi) stripT[mi * 16 + lm][w] = Tst[mi];
  }
  barrier_nd();

#pragma unroll
  for (int mi = 0; mi < 2; ++mi) {
    const int row = mi * 16 + lm;
    float c = baseL[row];
#pragma unroll
    for (int j4 = 0; j4 < 4; ++j4) {
      float4v s = *(const float4v*)&stripT[row][j4 * 4];
      c += (w > j4 * 4 + 0 ? s.x : 0.f) + (w > j4 * 4 + 1 ? s.y : 0.f) +
           (w > j4 * 4 + 2 ? s.z : 0.f) + (w > j4 * 4 + 3 ? s.w : 0.f);
    }
#pragma unroll
    for (int ni = 0; ni < 2; ++ni) {
      float base = c + niPre[mi][ni] + Eq[mi][ni];
      float4v o = { runp[mi][ni][0] + base, runp[mi][ni][1] + base,
                    runp[mi][ni][2] + base, runp[mi][ni][3] + base };
      *(float4v*)(out + (size_t)(m0 + row) * DOUT + w * 32 + ni * 16 + q * 4) = o;
    }
  }
}

// ---------------------------------------------------------------------------
extern "C" void kernel_launch(void* const* d_in, const int* in_sizes, int n_in,
                              void* d_out, int out_size, void* d_ws, size_t ws_size,
                              hipStream_t stream) {
  const float* x   = (const float*)d_in[0];  // [8192,2048]
  const float* Wh  = (const float*)d_in[1];  // [512,2048]
  const float* bh  = (const float*)d_in[2];  // [512]
  const float* Wb0 = (const float*)d_in[3];  // [1,2048]
  const float* bb  = (const float*)d_in[4];  // [1]
  float* out = (float*)d_out;

  unsigned short* Wp = (unsigned short*)d_ws;   // 2 MiB fragment-packed W

  k_pack<<<dim3((DOUT * DIN) / (256 * 8)), dim3(256), 0, stream>>>(Wh, Wp);
  k_main<<<dim3(NROW / BM), dim3(1024), 0, stream>>>(x, Wp, bh, Wb0, bb, out);
}

// Round 10
// 41.177 us; speedup vs baseline: 1.4214x; 1.4214x over previous
//
#include <hip/hip_runtime.h>
#include <hip/hip_bf16.h>

// Problem: B=8192, DIM_IN=2048, DIM_OUT=512
//   hazards = relu(x @ W_h^T + b_h)            [8192,512]
//   out     = cumsum(hazards, axis=1) + (x @ W_base^T + b_base)
//
// Round 10: asm-pinned B/A loads with hand-counted vmcnt(5) (never 0 in the
// steady loop). Two statically-named register sets, 1-phase lookahead; the
// compiler cannot sink or drain the pipeline. A staged via tiny dbuf LDS,
// lgkmcnt-only barriers. Fused bias+relu+scan+base epilogue unchanged.

typedef __attribute__((ext_vector_type(8))) short        short8;
typedef __attribute__((ext_vector_type(4))) float        float4v;
typedef __attribute__((ext_vector_type(4))) float        f32x4;
typedef __attribute__((ext_vector_type(2))) float        float2v;
typedef __attribute__((ext_vector_type(4))) unsigned int uint4v;

#define DIN  2048
#define DOUT 512
#define NROW 8192
#define BM   32
#define NPH  (DIN / 64)   // 32 K-phases of 64

static __device__ __forceinline__ unsigned short f2bf(float f) {
  union { float f; unsigned int u; } v; v.f = f;
  unsigned int u = v.u;
  unsigned int r = (u + 0x7FFFu + ((u >> 16) & 1u)) >> 16;   // RNE
  return (unsigned short)r;
}

static __device__ __forceinline__ void barrier_nd() {
  asm volatile("s_waitcnt lgkmcnt(0)" ::: "memory");
  __builtin_amdgcn_s_barrier();
}

// ---- k_pack: W[512][2048] f32 -> fragment-packed bf16 ---------------------
// fragment (nt, ktp): nt = n>>4 (32), ktp = k>>5 (64).
// lane slot: n = nt*16 + (lane&15), k = ktp*32 + (lane>>4)*8 (+e)
// storage: Wp[ ((nt*64 + ktp)*64 + lane)*8 + e ] -> each frag = 1KB contig.
__global__ __launch_bounds__(256) void k_pack(const float* __restrict__ W,
                                              unsigned short* __restrict__ Wp) {
  int t    = blockIdx.x * 256 + threadIdx.x;   // 0..131071
  int lane = t & 63;
  int frag = t >> 6;
  int nt   = frag >> 6, ktp = frag & 63;
  int n = nt * 16 + (lane & 15);
  int k = ktp * 32 + (lane >> 4) * 8;
  const float* src = W + (size_t)n * DIN + k;
  float4v a = *(const float4v*)src;
  float4v b = *(const float4v*)(src + 4);
  unsigned short o[8] = { f2bf(a.x), f2bf(a.y), f2bf(a.z), f2bf(a.w),
                          f2bf(b.x), f2bf(b.y), f2bf(b.z), f2bf(b.w) };
  *(short8*)(Wp + (size_t)t * 8) = *(const short8*)o;
}

// ---- k_main: fused GEMM + bias + relu + row-scan + base -------------------
// grid 256 (BM=32 rows), 1024 threads = 16 waves; wave w owns cols 32w..32w+31
// (ni 0..1). acc[mi][ni]: out rows mi*16+(lane&15), cols ni*16+(lane>>4)*4+r.
__global__ __launch_bounds__(1024) void k_main(
    const float* __restrict__ x, const unsigned short* __restrict__ Wp,
    const float* __restrict__ b_h, const float* __restrict__ w_base,
    const float* __restrict__ b_base, float* __restrict__ out) {
  __shared__ unsigned short Aa[2][BM * 64];    // 2 x 4 KB, XOR-swizzled
  __shared__ float WbL[DIN];                   // 8 KB base weights
  __shared__ float stripT[BM][16];
  __shared__ float baseL[BM];

  const int tid  = threadIdx.x;
  const int lane = tid & 63;
  const int w    = tid >> 6;       // wave 0..15
  const int q    = lane >> 4;      // 0..3
  const int lm   = lane & 15;
  const int m0   = blockIdx.x * BM;

  // A staging: row sr = tid>>5 (0..31), 2 k-cols at c2 = (tid&31)*2
  const int sr  = tid >> 5;
  const int c2  = (tid & 31) * 2;
  const int sgA = c2 >> 3;
  const int aOff = sr * 64 + ((sgA ^ (sr & 7)) << 3) + (c2 & 7);  // ushort idx

  // WbL fill: plain loads STRICTLY BEFORE any asm load (vmcnt bookkeeping)
  ((float2v*)WbL)[tid] = ((const float2v*)w_base)[tid];

  f32x4 acc[2][2];
  const f32x4 z4 = {0.f, 0.f, 0.f, 0.f};
#pragma unroll
  for (int mi = 0; mi < 2; ++mi)
#pragma unroll
    for (int ni = 0; ni < 2; ++ni) acc[mi][ni] = z4;

  // running addresses (byte pointers)
  const char* pB0 = (const char*)Wp + (size_t)(2 * w) * 65536 + lane * 16;
  const char* pB1 = (const char*)Wp + (size_t)(2 * w + 1) * 65536 + lane * 16;
  const char* pA  = (const char*)(x + (size_t)(m0 + sr) * DIN + c2);

  struct BA { uint4v b0, b1, b2, b3; float2v a; };
  BA s0, s1;

  float basePart = 0.f;

  auto issue = [&](BA& d) {   // 4 B-frags + 1 A pair, asm-pinned
    asm volatile("global_load_dwordx4 %0, %1, off"
                 : "=v"(d.b0) : "v"(pB0) : "memory");
    asm volatile("global_load_dwordx4 %0, %1, off offset:1024"
                 : "=v"(d.b1) : "v"(pB0) : "memory");
    asm volatile("global_load_dwordx4 %0, %1, off"
                 : "=v"(d.b2) : "v"(pB1) : "memory");
    asm volatile("global_load_dwordx4 %0, %1, off offset:1024"
                 : "=v"(d.b3) : "v"(pB1) : "memory");
    asm volatile("global_load_dwordx2 %0, %1, off"
                 : "=v"(d.a) : "v"(pA) : "memory");
    pB0 += 2048; pB1 += 2048; pA += 256;
  };

  auto mfma16 = [&](const BA& c, const unsigned short* Ac) {
    short8 xf0[2], xf1[2];   // [h][mi] -> xf{h}[mi]
#pragma unroll
    for (int mi = 0; mi < 2; ++mi) {
      int r = mi * 16 + lm;
      xf0[mi] = *(const short8*)&Ac[r * 64 + (((q)     ^ (r & 7)) << 3)];
      xf1[mi] = *(const short8*)&Ac[r * 64 + (((q + 4) ^ (r & 7)) << 3)];
    }
    const short8 sb0 = __builtin_bit_cast(short8, c.b0);  // ni0,h0
    const short8 sb1 = __builtin_bit_cast(short8, c.b1);  // ni0,h1
    const short8 sb2 = __builtin_bit_cast(short8, c.b2);  // ni1,h0
    const short8 sb3 = __builtin_bit_cast(short8, c.b3);  // ni1,h1
#pragma unroll
    for (int mi = 0; mi < 2; ++mi) {
      acc[mi][0] = __builtin_amdgcn_mfma_f32_16x16x32_bf16(sb0, xf0[mi], acc[mi][0], 0, 0, 0);
      acc[mi][1] = __builtin_amdgcn_mfma_f32_16x16x32_bf16(sb2, xf0[mi], acc[mi][1], 0, 0, 0);
      acc[mi][0] = __builtin_amdgcn_mfma_f32_16x16x32_bf16(sb1, xf1[mi], acc[mi][0], 0, 0, 0);
      acc[mi][1] = __builtin_amdgcn_mfma_f32_16x16x32_bf16(sb3, xf1[mi], acc[mi][1], 0, 0, 0);
    }
  };

  auto stageA = [&](const float2v& a, unsigned short* Ad, int p) {
    unsigned int pk = ((unsigned int)f2bf(a.x)) |
                      (((unsigned int)f2bf(a.y)) << 16);
    *(unsigned int*)&Ad[aOff] = pk;
    float2v wb = *(const float2v*)&WbL[p * 64 + c2];
    basePart += a.x * wb.x + a.y * wb.y;
  };

  // -------- prologue --------
  issue(s0);                       // phase 0 -> out 5
  issue(s1);                       // phase 1 -> out 10
  asm volatile("s_waitcnt vmcnt(5)" ::: "memory");   // s0 landed
  __builtin_amdgcn_sched_barrier(0);
  barrier_nd();                    // WbL visible to all waves
  stageA(s0.a, Aa[0], 0);
  barrier_nd();                    // Aa[0] staged

  // -------- bodies 0..29 (15 x 2, full form: issue p+2, vmcnt(5)) --------
  for (int it = 0; it < 15; ++it) {
    const int p = it * 2;
    {  // body p (even): cur=s0, nxt=s1
      mfma16(s0, Aa[0]);
      issue(s0);                                   // phase p+2
      asm volatile("s_waitcnt vmcnt(5)" ::: "memory");  // {B,A}(p+1) landed
      __builtin_amdgcn_sched_barrier(0);
      stageA(s1.a, Aa[1], p + 1);
      barrier_nd();
    }
    {  // body p+1 (odd): cur=s1, nxt=s0
      mfma16(s1, Aa[1]);
      issue(s1);                                   // phase p+3
      asm volatile("s_waitcnt vmcnt(5)" ::: "memory");  // {B,A}(p+2) landed
      __builtin_amdgcn_sched_barrier(0);
      stageA(s0.a, Aa[0], p + 2);
      barrier_nd();
    }
  }

  // -------- body 30 (even, cur=s0): no issue, drain --------
  mfma16(s0, Aa[0]);
  asm volatile("s_waitcnt vmcnt(0)" ::: "memory");  // {B,A}(31) landed
  __builtin_amdgcn_sched_barrier(0);
  stageA(s1.a, Aa[1], 31);
  barrier_nd();

  // -------- body 31 (odd, cur=s1): compute only --------
  mfma16(s1, Aa[1]);

  // ---- base GEMV reduce: 32 consecutive threads share row sr ----
  {
    float s = basePart;
    s += __shfl_xor(s, 1);  s += __shfl_xor(s, 2);
    s += __shfl_xor(s, 4);  s += __shfl_xor(s, 8);
    s += __shfl_xor(s, 16);
    if ((tid & 31) == 0) baseL[sr] = s + b_base[0];
  }

  // ---- epilogue: bias + relu + scan over this wave's 32-col strip ----
  float runp[2][2][4];
  float Eq[2][2];
  float niPre[2][2];
  float Tst[2];
#pragma unroll
  for (int mi = 0; mi < 2; ++mi) {
    float run = 0.f;
#pragma unroll
    for (int ni = 0; ni < 2; ++ni) {
      float4v b4 = *(const float4v*)(b_h + w * 32 + ni * 16 + q * 4);
      f32x4 v = acc[mi][ni];
      float h0 = fmaxf(v.x + b4.x, 0.f);
      float h1 = fmaxf(v.y + b4.y, 0.f);
      float h2 = fmaxf(v.z + b4.z, 0.f);
      float h3 = fmaxf(v.w + b4.w, 0.f);
      runp[mi][ni][0] = h0;
      runp[mi][ni][1] = h0 + h1;
      runp[mi][ni][2] = h0 + h1 + h2;
      runp[mi][ni][3] = h0 + h1 + h2 + h3;
      float S = runp[mi][ni][3];
      float u1 = __shfl_up(S, 16);
      float u2 = __shfl_up(S, 32);
      float u3 = __shfl_up(S, 48);
      Eq[mi][ni] = (q >= 1 ? u1 : 0.f) + (q >= 2 ? u2 : 0.f) + (q >= 3 ? u3 : 0.f);
      float G = S + __shfl_xor(S, 16);
      G += __shfl_xor(G, 32);
      niPre[mi][ni] = run;
      run += G;
    }
    Tst[mi] = run;
  }
  if (q == 0) {
#pragma unroll
    for (int mi = 0; mi < 2; ++mi) stripT[mi * 16 + lm][w] = Tst[mi];
  }
  barrier_nd();

#pragma unroll
  for (int mi = 0; mi < 2; ++mi) {
    const int row = mi * 16 + lm;
    float c = baseL[row];
#pragma unroll
    for (int j4 = 0; j4 < 4; ++j4) {
      float4v s = *(const float4v*)&stripT[row][j4 * 4];
      c += (w > j4 * 4 + 0 ? s.x : 0.f) + (w > j4 * 4 + 1 ? s.y : 0.f) +
           (w > j4 * 4 + 2 ? s.z : 0.f) + (w > j4 * 4 + 3 ? s.w : 0.f);
    }
#pragma unroll
    for (int ni = 0; ni < 2; ++ni) {
      float base = c + niPre[mi][ni] + Eq[mi][ni];
      float4v o = { runp[mi][ni][0] + base, runp[mi][ni][1] + base,
                    runp[mi][ni][2] + base, runp[mi][ni][3] + base };
      *(float4v*)(out + (size_t)(m0 + row) * DOUT + w * 32 + ni * 16 + q * 4) = o;
    }
  }
}

// ---------------------------------------------------------------------------
extern "C" void kernel_launch(void* const* d_in, const int* in_sizes, int n_in,
                              void* d_out, int out_size, void* d_ws, size_t ws_size,
                              hipStream_t stream) {
  const float* x   = (const float*)d_in[0];  // [8192,2048]
  const float* Wh  = (const float*)d_in[1];  // [512,2048]
  const float* bh  = (const float*)d_in[2];  // [512]
  const float* Wb0 = (const float*)d_in[3];  // [1,2048]
  const float* bb  = (const float*)d_in[4];  // [1]
  float* out = (float*)d_out;

  unsigned short* Wp = (unsigned short*)d_ws;   // 2 MiB fragment-packed W

  k_pack<<<dim3((DOUT * DIN) / (256 * 8)), dim3(256), 0, stream>>>(Wh, Wp);
  k_main<<<dim3(NROW / BM), dim3(1024), 0, stream>>>(x, Wp, bh, Wb0, bb, out);
}